// Round 7
// baseline (174.951 us; speedup 1.0000x reference)
//
#include <hip/hip_runtime.h>
#include <math.h>

#define KS   15
#define RAD  7
#define L    160
#define VOL  (L*L*L)
#define NB   4
#define HTL  40             // output h-rows per k_wh block
#define HALO (HTL + 2*RAD)  // 54
#define WTL  32             // w-cols per k_wh block
#define RPT  5              // h-rows per thread in stage B (8 ty-groups * 5 = 40)
#define DT   40             // k_d d-chunk per thread
#define NBLK (5*10*16)      // k_d grid blocks = 800

struct Taps {
    float g[KS];   // normalized 1D gaussian (symmetric)
    float h[KS];   // (x^2 - s^2)/s^4 * g (symmetric)
    float m;       // kernel mean (subtracted constant)
    float scale;   // 1 / (N * VOL)
};

// zero-padded float4 load from a row of length L
__device__ __forceinline__ float4 ld4z(const float* __restrict__ p, int w) {
    if (w >= 0 && w + 3 < L) return *reinterpret_cast<const float4*>(p + w);
    float4 r;
    r.x = (w     >= 0 && w     < L) ? p[w]     : 0.f;
    r.y = (w + 1 >= 0 && w + 1 < L) ? p[w + 1] : 0.f;
    r.z = (w + 2 >= 0 && w + 2 < L) ? p[w + 2] : 0.f;
    r.w = (w + 3 >= 0 && w + 3 < L) ? p[w + 3] : 0.f;
    return r;
}

// ============ Kernel 1: diff + W-conv + H-conv fused ========================
// grid (20 = 5 w-tiles x 4 h-tiles, 160 d, 4 n), block 256.
// LDS 20.7 KB -> up to 7 blocks/CU. Writes P,Q,R TRANSPOSED [n][h][d][w].
__global__ __launch_bounds__(256) void k_wh(const float* __restrict__ pred,
                                            const float* __restrict__ tgt,
                                            float* __restrict__ P,
                                            float* __restrict__ Q,
                                            float* __restrict__ R,
                                            Taps tp) {
    __shared__ float sA[HALO][WTL];
    __shared__ float sB[HALO][WTL];
    __shared__ float sC[HALO][WTL];

    const int tid = threadIdx.x;
    const int wt  = blockIdx.x >> 2;          // 0..4
    const int ht  = blockIdx.x & 3;           // 0..3
    const int wb  = wt * WTL;
    const int h0  = ht * HTL;
    const int d   = blockIdx.y;
    const int n   = blockIdx.z;
    const size_t nbase = (size_t)n * VOL;
    const float* __restrict__ pro = pred + nbase + (size_t)d * L * L;
    const float* __restrict__ tro = tgt  + nbase + (size_t)d * L * L;
    const bool wedge = (wt == 0) || (wt == 4);

    // ---- Stage A: diff + W-conv. 54 rows x 8 j-groups, 4 outputs/task ----
    for (int t = tid; t < HALO * 8; t += 256) {
        const int r = t >> 3;                 // 0..53
        const int j = t & 7;                  // 0..7
        const int h = h0 - RAD + r;
        float a[4], b[4], c[4];
        if (h >= 0 && h < L) {
            const float* pr = pro + h * L;
            const float* tr = tro + h * L;
            const int w0 = wb + 4 * j - 8;    // window base
            float dv[20];
            if (!wedge) {
#pragma unroll
                for (int q5 = 0; q5 < 5; ++q5) {
                    float4 pv = *reinterpret_cast<const float4*>(pr + w0 + 4 * q5);
                    float4 tv = *reinterpret_cast<const float4*>(tr + w0 + 4 * q5);
                    dv[4*q5+0] = pv.x - tv.x;
                    dv[4*q5+1] = pv.y - tv.y;
                    dv[4*q5+2] = pv.z - tv.z;
                    dv[4*q5+3] = pv.w - tv.w;
                }
            } else {
#pragma unroll
                for (int q5 = 0; q5 < 5; ++q5) {
                    float4 pv = ld4z(pr, w0 + 4 * q5);
                    float4 tv = ld4z(tr, w0 + 4 * q5);
                    dv[4*q5+0] = pv.x - tv.x;
                    dv[4*q5+1] = pv.y - tv.y;
                    dv[4*q5+2] = pv.z - tv.z;
                    dv[4*q5+3] = pv.w - tv.w;
                }
            }
#pragma unroll
            for (int k = 0; k < 4; ++k) {
                float mid = dv[k + 8];
                float aa = tp.g[7] * mid;
                float bb = tp.h[7] * mid;
                float cc = mid;
#pragma unroll
                for (int u = 0; u < 7; ++u) {     // symmetric taps
                    float s = dv[k + 1 + u] + dv[k + 15 - u];
                    aa += tp.g[u] * s;
                    bb += tp.h[u] * s;
                    cc += s;
                }
                a[k] = aa; b[k] = bb; c[k] = cc;
            }
        } else {
#pragma unroll
            for (int k = 0; k < 4; ++k) { a[k] = 0.f; b[k] = 0.f; c[k] = 0.f; }
        }
        *reinterpret_cast<float4*>(&sA[r][4*j]) = make_float4(a[0], a[1], a[2], a[3]);
        *reinterpret_cast<float4*>(&sB[r][4*j]) = make_float4(b[0], b[1], b[2], b[3]);
        *reinterpret_cast<float4*>(&sC[r][4*j]) = make_float4(c[0], c[1], c[2], c[3]);
    }
    __syncthreads();

    // ---- Stage B: H-conv; thread owns RPT consecutive h-rows at col tx ----
    {
        const int tx = tid & 31;
        const int ty = tid >> 5;              // 0..7
        float p[RPT], q[RPT], rb[RPT];
#pragma unroll
        for (int k = 0; k < RPT; ++k) { p[k] = 0.f; q[k] = 0.f; rb[k] = 0.f; }
#pragma unroll
        for (int jr = 0; jr < RPT + 2 * RAD; ++jr) {   // 19 rows
            const float va = sA[RPT * ty + jr][tx];
            const float vb = sB[RPT * ty + jr][tx];
            const float vc = sC[RPT * ty + jr][tx];
#pragma unroll
            for (int k = 0; k < RPT; ++k) {
                const int t = jr - k;
                if (t >= 0 && t < KS) {               // compile-time resolved
                    p[k]  += tp.g[t] * va;
                    q[k]  += tp.h[t] * va + tp.g[t] * vb;
                    rb[k] += vc;
                }
            }
        }
#pragma unroll
        for (int k = 0; k < RPT; ++k) {
            const int h = h0 + RPT * ty + k;
            const size_t o = nbase + ((size_t)h * L + d) * L + wb + tx;  // [n][h][d][w]
            P[o] = p[k]; Q[o] = q[k]; R[o] = rb[k];
        }
    }
}

// ============ Kernel 2: D-conv streaming + |.| + block reduce ================
__global__ __launch_bounds__(512) void k_d(const float* __restrict__ P,
                                           const float* __restrict__ Q,
                                           const float* __restrict__ R,
                                           float* __restrict__ partial,
                                           Taps tp) {
    const int tx = threadIdx.x;          // 0..31 (w)
    const int ty = threadIdx.y;          // 0..15 (h)
    const int w  = blockIdx.x * 32 + tx;
    const int h  = blockIdx.y * 16 + ty;
    const int gz = blockIdx.z;
    const int n  = gz >> 2;
    const int dc = gz & 3;
    const int d0 = dc * DT;

    const size_t base = (size_t)n * VOL + ((size_t)h * L) * L + w;
    const float* Pp = P + base;
    const float* Qp = Q + base;
    const float* Rp = R + base;

    float rp[KS], rq[KS], rc[KS];
    float box = 0.f;

#pragma unroll
    for (int i = 0; i < KS - 1; ++i) {
        int s = d0 - RAD + i;
        bool ok = (s >= 0);
        int off = s * L;
        float vp = ok ? Pp[off] : 0.f;
        float vq = ok ? Qp[off] : 0.f;
        float vc = ok ? Rp[off] : 0.f;
        rp[i] = vp; rq[i] = vq; rc[i] = vc;
        box += vc;
    }

    float acc = 0.f;
#pragma unroll
    for (int k = 0; k < DT; ++k) {
        int s = d0 + RAD + k;
        bool ok = (s < L);
        int off = s * L;
        float vp = ok ? Pp[off] : 0.f;
        float vq = ok ? Qp[off] : 0.f;
        float vc = ok ? Rp[off] : 0.f;
        const int ri = (KS - 1 + k) % KS;
        rp[ri] = vp; rq[ri] = vq; rc[ri] = vc;
        box += vc;

        float f = 0.f;
#pragma unroll
        for (int t = 0; t < KS; ++t) {
            const int ii = (k + t) % KS;
            f += tp.h[t] * rp[ii] + tp.g[t] * rq[ii];
        }
        f -= tp.m * box;
        acc += fabsf(f);

        box -= rc[k % KS];
    }
    acc *= tp.scale;

#pragma unroll
    for (int off = 32; off > 0; off >>= 1) acc += __shfl_down(acc, off);

    __shared__ float wsum[8];
    const int tid  = ty * 32 + tx;
    const int lane = tid & 63;
    const int wid  = tid >> 6;
    if (lane == 0) wsum[wid] = acc;
    __syncthreads();
    if (wid == 0) {
        float v = (lane < 8) ? wsum[lane] : 0.f;
#pragma unroll
        for (int off = 4; off > 0; off >>= 1) v += __shfl_down(v, off);
        if (lane == 0) {
            const int bid = (gz * gridDim.y + blockIdx.y) * gridDim.x + blockIdx.x;
            partial[bid] = v;
        }
    }
}

// ============ Final: sum 800 partials, single block, plain store ============
__global__ __launch_bounds__(1024) void k_reduce(const float* __restrict__ partial,
                                                 float* __restrict__ out) {
    float v = 0.f;
    for (int i = threadIdx.x; i < NBLK; i += 1024) v += partial[i];
#pragma unroll
    for (int off = 32; off > 0; off >>= 1) v += __shfl_down(v, off);

    __shared__ float wsum[16];
    const int lane = threadIdx.x & 63;
    const int wid  = threadIdx.x >> 6;
    if (lane == 0) wsum[wid] = v;
    __syncthreads();
    if (wid == 0) {
        float s = (lane < 16) ? wsum[lane] : 0.f;
#pragma unroll
        for (int off = 8; off > 0; off >>= 1) s += __shfl_down(s, off);
        if (lane == 0) out[0] = s;
    }
}

extern "C" void kernel_launch(void* const* d_in, const int* in_sizes, int n_in,
                              void* d_out, int out_size, void* d_ws, size_t ws_size,
                              hipStream_t stream) {
    const float* pred = (const float*)d_in[0];
    const float* tgt  = (const float*)d_in[1];
    float* out = (float*)d_out;
    float* ws  = (float*)d_ws;

    Taps tp;
    const double sigma = 1.5;
    double g1[KS], S = 0.0;
    for (int i = 0; i < KS; ++i) {
        double x = (double)(i - RAD);
        g1[i] = exp(-x * x / (2.0 * sigma * sigma));
        S += g1[i];
    }
    double sumH = 0.0;
    for (int i = 0; i < KS; ++i) {
        double x = (double)(i - RAD);
        double G = g1[i] / S;
        double H = (x * x - sigma * sigma) / (sigma * sigma * sigma * sigma) * G;
        tp.g[i] = (float)G;
        tp.h[i] = (float)H;
        sumH += H;
    }
    tp.m     = (float)(3.0 * sumH / (double)(KS * KS * KS));
    tp.scale = 1.0f / ((float)NB * (float)VOL);

    // ws: P[4*VOL] | Q[4*VOL] | R[4*VOL] | partial[800]
    float* Pb      = ws + (size_t)0 * NB * VOL;
    float* Qb      = ws + (size_t)1 * NB * VOL;
    float* Rb      = ws + (size_t)2 * NB * VOL;
    float* partial = ws + (size_t)3 * NB * VOL;

    k_wh<<<dim3(20, L, NB), dim3(256), 0, stream>>>(pred, tgt, Pb, Qb, Rb, tp);
    k_d<<<dim3(5, 10, NB * 4), dim3(32, 16), 0, stream>>>(Pb, Qb, Rb, partial, tp);
    k_reduce<<<1, 1024, 0, stream>>>(partial, out);
}

// Round 8
// 151.804 us; speedup vs baseline: 1.1525x; 1.1525x over previous
//
#include <hip/hip_runtime.h>
#include <hip/hip_fp16.h>
#include <math.h>

#define KS   15
#define RAD  7
#define L    160
#define VOL  (L*L*L)
#define NB   4
#define HTL  40             // output h-rows per k_wh block
#define HALO (HTL + 2*RAD)  // 54
#define WTL  32             // w-cols per k_wh block
#define RPT  5              // h-rows per thread in stage B
#define DT   40             // k_d d-chunk per thread
#define NBLK (5*10*16)      // k_d grid blocks = 800

struct Taps {
    float g[KS];   // normalized 1D gaussian (symmetric)
    float h[KS];   // (x^2 - s^2)/s^4 * g (symmetric)
    float m;       // kernel mean (subtracted constant)
    float scale;   // 1 / (N * VOL)
};

// zero-padded float4 load from a row of length L
__device__ __forceinline__ float4 ld4z(const float* __restrict__ p, int w) {
    if (w >= 0 && w + 3 < L) return *reinterpret_cast<const float4*>(p + w);
    float4 r;
    r.x = (w     >= 0 && w     < L) ? p[w]     : 0.f;
    r.y = (w + 1 >= 0 && w + 1 < L) ? p[w + 1] : 0.f;
    r.z = (w + 2 >= 0 && w + 2 < L) ? p[w + 2] : 0.f;
    r.w = (w + 3 >= 0 && w + 3 < L) ? p[w + 3] : 0.f;
    return r;
}

// ============ Kernel 1: diff + W-conv + H-conv fused ========================
// grid (20 = 5 w-tiles x 4 h-tiles, 160 d, 4 n), block 256.
// Writes PQ (half2) and R (half), TRANSPOSED [n][h][d][w].
__global__ __launch_bounds__(256) void k_wh(const float* __restrict__ pred,
                                            const float* __restrict__ tgt,
                                            __half2* __restrict__ PQ,
                                            __half* __restrict__ Rb,
                                            Taps tp) {
    __shared__ float sA[HALO][WTL];
    __shared__ float sB[HALO][WTL];
    __shared__ float sC[HALO][WTL];

    const int tid = threadIdx.x;
    const int wt  = blockIdx.x >> 2;          // 0..4
    const int ht  = blockIdx.x & 3;           // 0..3
    const int wb  = wt * WTL;
    const int h0  = ht * HTL;
    const int d   = blockIdx.y;
    const int n   = blockIdx.z;
    const size_t nbase = (size_t)n * VOL;
    const float* __restrict__ pro = pred + nbase + (size_t)d * L * L;
    const float* __restrict__ tro = tgt  + nbase + (size_t)d * L * L;
    const bool wedge = (wt == 0) || (wt == 4);

    // ---- Stage A: diff + W-conv. 54 rows x 4 groups, 8 outputs/task ----
    // 216 tasks <= 256 threads: exactly one task per thread (uniform).
    if (tid < HALO * 4) {
        const int r  = tid >> 2;              // 0..53
        const int j2 = tid & 3;               // 0..3
        const int h  = h0 - RAD + r;
        float a[8], b[8], c[8];
        if (h >= 0 && h < L) {
            const float* pr = pro + h * L;
            const float* tr = tro + h * L;
            const int w0 = wb + 8 * j2 - 8;   // 24-float window base (8-aligned)
            float dv[24];
            if (!wedge) {
#pragma unroll
                for (int q = 0; q < 6; ++q) {
                    float4 pv = *reinterpret_cast<const float4*>(pr + w0 + 4 * q);
                    float4 tv = *reinterpret_cast<const float4*>(tr + w0 + 4 * q);
                    dv[4*q+0] = pv.x - tv.x;
                    dv[4*q+1] = pv.y - tv.y;
                    dv[4*q+2] = pv.z - tv.z;
                    dv[4*q+3] = pv.w - tv.w;
                }
            } else {
#pragma unroll
                for (int q = 0; q < 6; ++q) {
                    float4 pv = ld4z(pr, w0 + 4 * q);
                    float4 tv = ld4z(tr, w0 + 4 * q);
                    dv[4*q+0] = pv.x - tv.x;
                    dv[4*q+1] = pv.y - tv.y;
                    dv[4*q+2] = pv.z - tv.z;
                    dv[4*q+3] = pv.w - tv.w;
                }
            }
#pragma unroll
            for (int k = 0; k < 8; ++k) {     // output w = wb + 8*j2 + k
                float mid = dv[k + 8];
                float aa = tp.g[7] * mid;
                float bb = tp.h[7] * mid;
                float cc = mid;
#pragma unroll
                for (int u = 0; u < 7; ++u) { // symmetric taps
                    float s = dv[k + 1 + u] + dv[k + 15 - u];
                    aa += tp.g[u] * s;
                    bb += tp.h[u] * s;
                    cc += s;
                }
                a[k] = aa; b[k] = bb; c[k] = cc;
            }
        } else {
#pragma unroll
            for (int k = 0; k < 8; ++k) { a[k] = 0.f; b[k] = 0.f; c[k] = 0.f; }
        }
        *reinterpret_cast<float4*>(&sA[r][8*j2  ]) = make_float4(a[0], a[1], a[2], a[3]);
        *reinterpret_cast<float4*>(&sA[r][8*j2+4]) = make_float4(a[4], a[5], a[6], a[7]);
        *reinterpret_cast<float4*>(&sB[r][8*j2  ]) = make_float4(b[0], b[1], b[2], b[3]);
        *reinterpret_cast<float4*>(&sB[r][8*j2+4]) = make_float4(b[4], b[5], b[6], b[7]);
        *reinterpret_cast<float4*>(&sC[r][8*j2  ]) = make_float4(c[0], c[1], c[2], c[3]);
        *reinterpret_cast<float4*>(&sC[r][8*j2+4]) = make_float4(c[4], c[5], c[6], c[7]);
    }
    __syncthreads();

    // ---- Stage B: H-conv; thread owns RPT consecutive h-rows at col tx ----
    {
        const int tx = tid & 31;
        const int ty = tid >> 5;              // 0..7
        float p[RPT], q[RPT], rb[RPT];
#pragma unroll
        for (int k = 0; k < RPT; ++k) { p[k] = 0.f; q[k] = 0.f; rb[k] = 0.f; }
#pragma unroll
        for (int jr = 0; jr < RPT + 2 * RAD; ++jr) {   // 19 rows
            const float va = sA[RPT * ty + jr][tx];
            const float vb = sB[RPT * ty + jr][tx];
            const float vc = sC[RPT * ty + jr][tx];
#pragma unroll
            for (int k = 0; k < RPT; ++k) {
                const int t = jr - k;
                if (t >= 0 && t < KS) {               // compile-time resolved
                    p[k]  += tp.g[t] * va;
                    q[k]  += tp.h[t] * va + tp.g[t] * vb;
                    rb[k] += vc;
                }
            }
        }
#pragma unroll
        for (int k = 0; k < RPT; ++k) {
            const int h = h0 + RPT * ty + k;
            const size_t o = nbase + ((size_t)h * L + d) * L + wb + tx;  // [n][h][d][w]
            PQ[o] = __floats2half2_rn(p[k], q[k]);
            Rb[o] = __float2half_rn(rb[k]);
        }
    }
}

// ============ Kernel 2: D-conv streaming + |.| + block reduce ================
__global__ __launch_bounds__(512) void k_d(const __half2* __restrict__ PQ,
                                           const __half* __restrict__ R,
                                           float* __restrict__ partial,
                                           Taps tp) {
    const int tx = threadIdx.x;          // 0..31 (w)
    const int ty = threadIdx.y;          // 0..15 (h)
    const int w  = blockIdx.x * 32 + tx;
    const int h  = blockIdx.y * 16 + ty;
    const int gz = blockIdx.z;
    const int n  = gz >> 2;
    const int dc = gz & 3;
    const int d0 = dc * DT;

    const size_t base = (size_t)n * VOL + ((size_t)h * L) * L + w;
    const __half2* PQp = PQ + base;
    const __half*  Rp  = R  + base;

    float rp[KS], rq[KS], rc[KS];
    float box = 0.f;

#pragma unroll
    for (int i = 0; i < KS - 1; ++i) {
        int s = d0 - RAD + i;
        bool ok = (s >= 0);
        int off = s * L;
        float2 pq = make_float2(0.f, 0.f);
        float vc = 0.f;
        if (ok) {
            pq = __half22float2(PQp[off]);
            vc = __half2float(Rp[off]);
        }
        rp[i] = pq.x; rq[i] = pq.y; rc[i] = vc;
        box += vc;
    }

    float acc = 0.f;
#pragma unroll
    for (int k = 0; k < DT; ++k) {
        int s = d0 + RAD + k;
        bool ok = (s < L);
        int off = s * L;
        float2 pq = make_float2(0.f, 0.f);
        float vc = 0.f;
        if (ok) {
            pq = __half22float2(PQp[off]);
            vc = __half2float(Rp[off]);
        }
        const int ri = (KS - 1 + k) % KS;
        rp[ri] = pq.x; rq[ri] = pq.y; rc[ri] = vc;
        box += vc;

        float f = 0.f;
#pragma unroll
        for (int t = 0; t < KS; ++t) {
            const int ii = (k + t) % KS;
            f += tp.h[t] * rp[ii] + tp.g[t] * rq[ii];
        }
        f -= tp.m * box;
        acc += fabsf(f);

        box -= rc[k % KS];
    }
    acc *= tp.scale;

#pragma unroll
    for (int off = 32; off > 0; off >>= 1) acc += __shfl_down(acc, off);

    __shared__ float wsum[8];
    const int tid  = ty * 32 + tx;
    const int lane = tid & 63;
    const int wid  = tid >> 6;
    if (lane == 0) wsum[wid] = acc;
    __syncthreads();
    if (wid == 0) {
        float v = (lane < 8) ? wsum[lane] : 0.f;
#pragma unroll
        for (int off = 4; off > 0; off >>= 1) v += __shfl_down(v, off);
        if (lane == 0) {
            const int bid = (gz * gridDim.y + blockIdx.y) * gridDim.x + blockIdx.x;
            partial[bid] = v;
        }
    }
}

// ============ Final: sum 800 partials, single block, plain store ============
__global__ __launch_bounds__(1024) void k_reduce(const float* __restrict__ partial,
                                                 float* __restrict__ out) {
    float v = 0.f;
    for (int i = threadIdx.x; i < NBLK; i += 1024) v += partial[i];
#pragma unroll
    for (int off = 32; off > 0; off >>= 1) v += __shfl_down(v, off);

    __shared__ float wsum[16];
    const int lane = threadIdx.x & 63;
    const int wid  = threadIdx.x >> 6;
    if (lane == 0) wsum[wid] = v;
    __syncthreads();
    if (wid == 0) {
        float s = (lane < 16) ? wsum[lane] : 0.f;
#pragma unroll
        for (int off = 8; off > 0; off >>= 1) s += __shfl_down(s, off);
        if (lane == 0) out[0] = s;
    }
}

extern "C" void kernel_launch(void* const* d_in, const int* in_sizes, int n_in,
                              void* d_out, int out_size, void* d_ws, size_t ws_size,
                              hipStream_t stream) {
    const float* pred = (const float*)d_in[0];
    const float* tgt  = (const float*)d_in[1];
    float* out = (float*)d_out;

    Taps tp;
    const double sigma = 1.5;
    double g1[KS], S = 0.0;
    for (int i = 0; i < KS; ++i) {
        double x = (double)(i - RAD);
        g1[i] = exp(-x * x / (2.0 * sigma * sigma));
        S += g1[i];
    }
    double sumH = 0.0;
    for (int i = 0; i < KS; ++i) {
        double x = (double)(i - RAD);
        double G = g1[i] / S;
        double H = (x * x - sigma * sigma) / (sigma * sigma * sigma * sigma) * G;
        tp.g[i] = (float)G;
        tp.h[i] = (float)H;
        sumH += H;
    }
    tp.m     = (float)(3.0 * sumH / (double)(KS * KS * KS));
    tp.scale = 1.0f / ((float)NB * (float)VOL);

    // ws layout (bytes): PQ half2 [NB*VOL*4] | R half [NB*VOL*2] | partial f32
    char* wsb = (char*)d_ws;
    __half2* PQ      = (__half2*)wsb;
    __half*  Rb      = (__half*)(wsb + (size_t)NB * VOL * 4);
    float*   partial = (float*)(wsb + (size_t)NB * VOL * 6);

    k_wh<<<dim3(20, L, NB), dim3(256), 0, stream>>>(pred, tgt, PQ, Rb, tp);
    k_d<<<dim3(5, 10, NB * 4), dim3(32, 16), 0, stream>>>(PQ, Rb, partial, tp);
    k_reduce<<<1, 1024, 0, stream>>>(partial, out);
}

// Round 9
// 131.130 us; speedup vs baseline: 1.3342x; 1.1577x over previous
//
#include <hip/hip_runtime.h>
#include <hip/hip_fp16.h>
#include <math.h>

#define KS   15
#define RAD  7
#define L    160
#define VOL  (L*L*L)
#define NB   4
#define WTL  32             // w-cols per k_wh block
#define HALO (L + 2*RAD)    // 174 rows (full h column + halo)
#define RPT  5              // h-rows per thread in stage B (32 ty * 5 = 160)
#define DT   40             // k_d d-chunk per thread
#define NBLK (5*10*16)      // k_d grid blocks = 800

typedef float fx2 __attribute__((ext_vector_type(2)));
typedef float fx4 __attribute__((ext_vector_type(4)));

struct Taps {
    float g[KS];   // normalized 1D gaussian (symmetric)
    float h[KS];   // (x^2 - s^2)/s^4 * g (symmetric)
    float m;       // kernel mean (subtracted constant)
    float scale;   // 1 / (N * VOL)
};

// zero-padded fx4 load from a row of length L
__device__ __forceinline__ fx4 ld4z(const float* __restrict__ p, int w) {
    if (w >= 0 && w + 3 < L) return *reinterpret_cast<const fx4*>(p + w);
    fx4 r;
    r.x = (w     >= 0 && w     < L) ? p[w]     : 0.f;
    r.y = (w + 1 >= 0 && w + 1 < L) ? p[w + 1] : 0.f;
    r.z = (w + 2 >= 0 && w + 2 < L) ? p[w + 2] : 0.f;
    r.w = (w + 3 >= 0 && w + 3 < L) ? p[w + 3] : 0.f;
    return r;
}

// ============ Kernel 1: diff + W-conv + H-conv fused ========================
// grid (5 w-tiles, 160 d, 4 n), block 256. Full h-column per block.
// Writes PQ (half2) and R (half), TRANSPOSED [n][h][d][w].
__global__ __launch_bounds__(256) void k_wh(const float* __restrict__ pred,
                                            const float* __restrict__ tgt,
                                            __half2* __restrict__ PQ,
                                            __half* __restrict__ Rb,
                                            Taps tp) {
    __shared__ float   sA[HALO][WTL];
    __shared__ float   sB[HALO][WTL];
    __shared__ __half2 sC[HALO][WTL / 2];

    const int tid = threadIdx.x;
    const int wt  = blockIdx.x;               // 0..4
    const int wb  = wt * WTL;
    const int d   = blockIdx.y;
    const int n   = blockIdx.z;
    const size_t nbase = (size_t)n * VOL;
    const float* __restrict__ pro = pred + nbase + (size_t)d * L * L;
    const float* __restrict__ tro = tgt  + nbase + (size_t)d * L * L;
    const bool wedge = (wt == 0) || (wt == 4);

    // ---- Stage A: diff + W-conv. 174 rows x 4 groups, 8 outputs/task ----
    for (int task = tid; task < HALO * 4; task += 256) {
        const int r  = task >> 2;             // 0..173
        const int j2 = task & 3;              // 0..3
        const int h  = r - RAD;
        if (h >= 0 && h < L) {
            const float* pr = pro + h * L;
            const float* tr = tro + h * L;
            const int w0 = wb + 8 * j2 - 8;   // 24-float window base
            float dv[24];
            if (!wedge) {
#pragma unroll
                for (int q = 0; q < 6; ++q) {
                    fx4 pv = *reinterpret_cast<const fx4*>(pr + w0 + 4 * q);
                    fx4 tv = *reinterpret_cast<const fx4*>(tr + w0 + 4 * q);
                    fx4 dd = pv - tv;         // packed f32 sub
                    dv[4*q+0] = dd.x; dv[4*q+1] = dd.y;
                    dv[4*q+2] = dd.z; dv[4*q+3] = dd.w;
                }
            } else {
#pragma unroll
                for (int q = 0; q < 6; ++q) {
                    fx4 pv = ld4z(pr, w0 + 4 * q);
                    fx4 tv = ld4z(tr, w0 + 4 * q);
                    fx4 dd = pv - tv;
                    dv[4*q+0] = dd.x; dv[4*q+1] = dd.y;
                    dv[4*q+2] = dd.z; dv[4*q+3] = dd.w;
                }
            }
            // conv over k-pairs with packed f32 (v_pk_fma_f32)
#pragma unroll
            for (int kp = 0; kp < 8; kp += 2) {
                fx2 mid = {dv[kp + 8], dv[kp + 9]};
                fx2 aa = tp.g[7] * mid;
                fx2 bb = tp.h[7] * mid;
                fx2 cc = mid;
#pragma unroll
                for (int u = 0; u < 7; ++u) {         // symmetric taps
                    fx2 sl = {dv[kp + 1 + u],  dv[kp + 2 + u]};
                    fx2 sr = {dv[kp + 15 - u], dv[kp + 16 - u]};
                    fx2 s  = sl + sr;
                    aa += tp.g[u] * s;
                    bb += tp.h[u] * s;
                    cc += s;
                }
                *reinterpret_cast<fx2*>(&sA[r][8*j2 + kp]) = aa;
                *reinterpret_cast<fx2*>(&sB[r][8*j2 + kp]) = bb;
                sC[r][(8*j2 + kp) >> 1] = __floats2half2_rn(cc.x, cc.y);
            }
        } else {
#pragma unroll
            for (int kp = 0; kp < 8; kp += 2) {
                fx2 z = {0.f, 0.f};
                *reinterpret_cast<fx2*>(&sA[r][8*j2 + kp]) = z;
                *reinterpret_cast<fx2*>(&sB[r][8*j2 + kp]) = z;
                sC[r][(8*j2 + kp) >> 1] = __floats2half2_rn(0.f, 0.f);
            }
        }
    }
    __syncthreads();

    // ---- Stage B: H-conv; thread owns 4 w-cols x RPT h-rows ----
    {
        const int wg = tid & 7;               // 0..7 -> w = wb + 4*wg .. +3
        const int ty = tid >> 3;              // 0..31 -> h = 5*ty .. +4
        fx2 p[RPT][2], q[RPT][2], rb[RPT][2];
#pragma unroll
        for (int k = 0; k < RPT; ++k) {
            p[k][0] = 0.f; p[k][1] = 0.f;
            q[k][0] = 0.f; q[k][1] = 0.f;
            rb[k][0] = 0.f; rb[k][1] = 0.f;
        }
#pragma unroll
        for (int jr = 0; jr < RPT + 2 * RAD; ++jr) {   // 19 rows
            const int srow = RPT * ty + jr;
            fx4 va4 = *reinterpret_cast<const fx4*>(&sA[srow][4*wg]);
            fx4 vb4 = *reinterpret_cast<const fx4*>(&sB[srow][4*wg]);
            fx2 va_lo = __builtin_shufflevector(va4, va4, 0, 1);
            fx2 va_hi = __builtin_shufflevector(va4, va4, 2, 3);
            fx2 vb_lo = __builtin_shufflevector(vb4, vb4, 0, 1);
            fx2 vb_hi = __builtin_shufflevector(vb4, vb4, 2, 3);
            const __half2* cp = &sC[srow][2*wg];
            float2 c0 = __half22float2(cp[0]);
            float2 c1 = __half22float2(cp[1]);
            fx2 vc_lo = {c0.x, c0.y};
            fx2 vc_hi = {c1.x, c1.y};
#pragma unroll
            for (int k = 0; k < RPT; ++k) {
                const int t = jr - k;
                if (t >= 0 && t < KS) {               // compile-time resolved
                    p[k][0]  += tp.g[t] * va_lo;
                    p[k][1]  += tp.g[t] * va_hi;
                    q[k][0]  += tp.h[t] * va_lo + tp.g[t] * vb_lo;
                    q[k][1]  += tp.h[t] * va_hi + tp.g[t] * vb_hi;
                    rb[k][0] += vc_lo;
                    rb[k][1] += vc_hi;
                }
            }
        }
#pragma unroll
        for (int k = 0; k < RPT; ++k) {
            const int h = RPT * ty + k;
            const size_t o = nbase + ((size_t)h * L + d) * L + wb + 4*wg;
            __half2 pq[4];
            pq[0] = __floats2half2_rn(p[k][0].x, q[k][0].x);
            pq[1] = __floats2half2_rn(p[k][0].y, q[k][0].y);
            pq[2] = __floats2half2_rn(p[k][1].x, q[k][1].x);
            pq[3] = __floats2half2_rn(p[k][1].y, q[k][1].y);
            *reinterpret_cast<int4*>(&PQ[o]) = *reinterpret_cast<int4*>(pq);
            __half2 rr[2];
            rr[0] = __floats2half2_rn(rb[k][0].x, rb[k][0].y);
            rr[1] = __floats2half2_rn(rb[k][1].x, rb[k][1].y);
            *reinterpret_cast<int2*>(&Rb[o]) = *reinterpret_cast<int2*>(rr);
        }
    }
}

// ============ Kernel 2: D-conv streaming + |.| + block reduce ================
__global__ __launch_bounds__(512) void k_d(const __half2* __restrict__ PQ,
                                           const __half* __restrict__ R,
                                           float* __restrict__ partial,
                                           Taps tp) {
    const int tx = threadIdx.x;          // 0..31 (w)
    const int ty = threadIdx.y;          // 0..15 (h)
    const int w  = blockIdx.x * 32 + tx;
    const int h  = blockIdx.y * 16 + ty;
    const int gz = blockIdx.z;
    const int n  = gz >> 2;
    const int dc = gz & 3;
    const int d0 = dc * DT;

    const size_t base = (size_t)n * VOL + ((size_t)h * L) * L + w;
    const __half2* PQp = PQ + base;
    const __half*  Rp  = R  + base;

    float rp[KS], rq[KS], rc[KS];
    float box = 0.f;

#pragma unroll
    for (int i = 0; i < KS - 1; ++i) {
        int s = d0 - RAD + i;
        bool ok = (s >= 0);
        int off = s * L;
        float2 pq = make_float2(0.f, 0.f);
        float vc = 0.f;
        if (ok) {
            pq = __half22float2(PQp[off]);
            vc = __half2float(Rp[off]);
        }
        rp[i] = pq.x; rq[i] = pq.y; rc[i] = vc;
        box += vc;
    }

    float acc = 0.f;
#pragma unroll
    for (int k = 0; k < DT; ++k) {
        int s = d0 + RAD + k;
        bool ok = (s < L);
        int off = s * L;
        float2 pq = make_float2(0.f, 0.f);
        float vc = 0.f;
        if (ok) {
            pq = __half22float2(PQp[off]);
            vc = __half2float(Rp[off]);
        }
        const int ri = (KS - 1 + k) % KS;
        rp[ri] = pq.x; rq[ri] = pq.y; rc[ri] = vc;
        box += vc;

        float f = 0.f;
#pragma unroll
        for (int t = 0; t < KS; ++t) {
            const int ii = (k + t) % KS;
            f += tp.h[t] * rp[ii] + tp.g[t] * rq[ii];
        }
        f -= tp.m * box;
        acc += fabsf(f);

        box -= rc[k % KS];
    }
    acc *= tp.scale;

#pragma unroll
    for (int off = 32; off > 0; off >>= 1) acc += __shfl_down(acc, off);

    __shared__ float wsum[8];
    const int tid  = ty * 32 + tx;
    const int lane = tid & 63;
    const int wid  = tid >> 6;
    if (lane == 0) wsum[wid] = acc;
    __syncthreads();
    if (wid == 0) {
        float v = (lane < 8) ? wsum[lane] : 0.f;
#pragma unroll
        for (int off = 4; off > 0; off >>= 1) v += __shfl_down(v, off);
        if (lane == 0) {
            const int bid = (gz * gridDim.y + blockIdx.y) * gridDim.x + blockIdx.x;
            partial[bid] = v;
        }
    }
}

// ============ Final: sum 800 partials, single block, plain store ============
__global__ __launch_bounds__(1024) void k_reduce(const float* __restrict__ partial,
                                                 float* __restrict__ out) {
    float v = 0.f;
    for (int i = threadIdx.x; i < NBLK; i += 1024) v += partial[i];
#pragma unroll
    for (int off = 32; off > 0; off >>= 1) v += __shfl_down(v, off);

    __shared__ float wsum[16];
    const int lane = threadIdx.x & 63;
    const int wid  = threadIdx.x >> 6;
    if (lane == 0) wsum[wid] = v;
    __syncthreads();
    if (wid == 0) {
        float s = (lane < 16) ? wsum[lane] : 0.f;
#pragma unroll
        for (int off = 8; off > 0; off >>= 1) s += __shfl_down(s, off);
        if (lane == 0) out[0] = s;
    }
}

extern "C" void kernel_launch(void* const* d_in, const int* in_sizes, int n_in,
                              void* d_out, int out_size, void* d_ws, size_t ws_size,
                              hipStream_t stream) {
    const float* pred = (const float*)d_in[0];
    const float* tgt  = (const float*)d_in[1];
    float* out = (float*)d_out;

    Taps tp;
    const double sigma = 1.5;
    double g1[KS], S = 0.0;
    for (int i = 0; i < KS; ++i) {
        double x = (double)(i - RAD);
        g1[i] = exp(-x * x / (2.0 * sigma * sigma));
        S += g1[i];
    }
    double sumH = 0.0;
    for (int i = 0; i < KS; ++i) {
        double x = (double)(i - RAD);
        double G = g1[i] / S;
        double H = (x * x - sigma * sigma) / (sigma * sigma * sigma * sigma) * G;
        tp.g[i] = (float)G;
        tp.h[i] = (float)H;
        sumH += H;
    }
    tp.m     = (float)(3.0 * sumH / (double)(KS * KS * KS));
    tp.scale = 1.0f / ((float)NB * (float)VOL);

    // ws layout (bytes): PQ half2 [NB*VOL*4] | R half [NB*VOL*2] | partial f32
    char* wsb = (char*)d_ws;
    __half2* PQ      = (__half2*)wsb;
    __half*  Rb      = (__half*)(wsb + (size_t)NB * VOL * 4);
    float*   partial = (float*)(wsb + (size_t)NB * VOL * 6);

    k_wh<<<dim3(5, L, NB), dim3(256), 0, stream>>>(pred, tgt, PQ, Rb, tp);
    k_d<<<dim3(5, 10, NB * 4), dim3(32, 16), 0, stream>>>(PQ, Rb, partial, tp);
    k_reduce<<<1, 1024, 0, stream>>>(partial, out);
}

// Round 10
// 128.142 us; speedup vs baseline: 1.3653x; 1.0233x over previous
//
#include <hip/hip_runtime.h>
#include <hip/hip_fp16.h>
#include <math.h>

#define KS   15
#define RAD  7
#define L    160
#define VOL  (L*L*L)
#define NB   4
#define WTL  32             // w-cols per k_wh block
#define HTL  80             // output h-rows per k_wh block
#define HALO (HTL + 2*RAD)  // 94
#define LDA  34             // LDS row stride in floats (even, bank-skewed)
#define RPT  5              // h-rows per thread in stage B (16 ty * 5 = 80)
#define DT   40             // k_d d-chunk per thread
#define NBLK (5*10*16)      // k_d grid blocks = 800

typedef float fx2 __attribute__((ext_vector_type(2)));
typedef float fx4 __attribute__((ext_vector_type(4)));

struct Taps {
    float g[KS];   // normalized 1D gaussian (symmetric)
    float h[KS];   // (x^2 - s^2)/s^4 * g (symmetric)
    float m;       // kernel mean (subtracted constant)
    float scale;   // 1 / (N * VOL)
};

// zero-padded fx4 load from a row of length L
__device__ __forceinline__ fx4 ld4z(const float* __restrict__ p, int w) {
    if (w >= 0 && w + 3 < L) return *reinterpret_cast<const fx4*>(p + w);
    fx4 r;
    r.x = (w     >= 0 && w     < L) ? p[w]     : 0.f;
    r.y = (w + 1 >= 0 && w + 1 < L) ? p[w + 1] : 0.f;
    r.z = (w + 2 >= 0 && w + 2 < L) ? p[w + 2] : 0.f;
    r.w = (w + 3 >= 0 && w + 3 < L) ? p[w + 3] : 0.f;
    return r;
}

// ============ Kernel 1: diff + W-conv + H-conv fused ========================
// grid (10 = 5 w-tiles x 2 h-tiles, 160 d, 4 n), block 256.
// LDS ~31.2 KB. Writes PQ (half2) and R (half), TRANSPOSED [n][h][d][w].
__global__ __launch_bounds__(256) void k_wh(const float* __restrict__ pred,
                                            const float* __restrict__ tgt,
                                            __half2* __restrict__ PQ,
                                            __half* __restrict__ Rb,
                                            Taps tp) {
    __shared__ float   sA[HALO][LDA];
    __shared__ float   sB[HALO][LDA];
    __shared__ __half2 sC[HALO][LDA / 2];

    const int tid = threadIdx.x;
    const int wt  = blockIdx.x >> 1;          // 0..4
    const int ht  = blockIdx.x & 1;           // 0..1
    const int wb  = wt * WTL;
    const int h0  = ht * HTL;
    const int d   = blockIdx.y;
    const int n   = blockIdx.z;
    const size_t nbase = (size_t)n * VOL;
    const float* __restrict__ pro = pred + nbase + (size_t)d * L * L;
    const float* __restrict__ tro = tgt  + nbase + (size_t)d * L * L;
    const bool wedge = (wt == 0) || (wt == 4);

    // ---- Stage A: diff + W-conv. 94 rows x 4 groups, 8 outputs/task ----
    for (int task = tid; task < HALO * 4; task += 256) {
        const int r  = task >> 2;             // 0..93
        const int j2 = task & 3;              // 0..3
        const int h  = h0 - RAD + r;
        if (h >= 0 && h < L) {
            const float* pr = pro + h * L;
            const float* tr = tro + h * L;
            const int w0 = wb + 8 * j2 - 8;   // 24-float window base
            float dv[24];
            if (!wedge) {
#pragma unroll
                for (int q = 0; q < 6; ++q) {
                    fx4 pv = *reinterpret_cast<const fx4*>(pr + w0 + 4 * q);
                    fx4 tv = *reinterpret_cast<const fx4*>(tr + w0 + 4 * q);
                    fx4 dd = pv - tv;         // packed f32 sub
                    dv[4*q+0] = dd.x; dv[4*q+1] = dd.y;
                    dv[4*q+2] = dd.z; dv[4*q+3] = dd.w;
                }
            } else {
#pragma unroll
                for (int q = 0; q < 6; ++q) {
                    fx4 pv = ld4z(pr, w0 + 4 * q);
                    fx4 tv = ld4z(tr, w0 + 4 * q);
                    fx4 dd = pv - tv;
                    dv[4*q+0] = dd.x; dv[4*q+1] = dd.y;
                    dv[4*q+2] = dd.z; dv[4*q+3] = dd.w;
                }
            }
            // conv over k-pairs with packed f32 (v_pk_fma_f32)
#pragma unroll
            for (int kp = 0; kp < 8; kp += 2) {
                fx2 mid = {dv[kp + 8], dv[kp + 9]};
                fx2 aa = tp.g[7] * mid;
                fx2 bb = tp.h[7] * mid;
                fx2 cc = mid;
#pragma unroll
                for (int u = 0; u < 7; ++u) {         // symmetric taps
                    fx2 sl = {dv[kp + 1 + u],  dv[kp + 2 + u]};
                    fx2 sr = {dv[kp + 15 - u], dv[kp + 16 - u]};
                    fx2 s  = sl + sr;
                    aa += tp.g[u] * s;
                    bb += tp.h[u] * s;
                    cc += s;
                }
                *reinterpret_cast<fx2*>(&sA[r][8*j2 + kp]) = aa;
                *reinterpret_cast<fx2*>(&sB[r][8*j2 + kp]) = bb;
                sC[r][(8*j2 + kp) >> 1] = __floats2half2_rn(cc.x, cc.y);
            }
        } else {
#pragma unroll
            for (int kp = 0; kp < 8; kp += 2) {
                fx2 z = {0.f, 0.f};
                *reinterpret_cast<fx2*>(&sA[r][8*j2 + kp]) = z;
                *reinterpret_cast<fx2*>(&sB[r][8*j2 + kp]) = z;
                sC[r][(8*j2 + kp) >> 1] = __floats2half2_rn(0.f, 0.f);
            }
        }
    }
    __syncthreads();

    // ---- Stage B: H-conv; thread owns 2 w-cols x RPT h-rows ----
    {
        const int wg = tid & 15;              // 0..15 -> w = wb + 2*wg, +1
        const int ty = tid >> 4;              // 0..15 -> h = h0 + 5*ty .. +4
        fx2 p[RPT], q[RPT], rb[RPT];
#pragma unroll
        for (int k = 0; k < RPT; ++k) { p[k] = 0.f; q[k] = 0.f; rb[k] = 0.f; }
#pragma unroll
        for (int jr = 0; jr < RPT + 2 * RAD; ++jr) {   // 19 rows
            const int srow = RPT * ty + jr;
            fx2 va = *reinterpret_cast<const fx2*>(&sA[srow][2*wg]);
            fx2 vb = *reinterpret_cast<const fx2*>(&sB[srow][2*wg]);
            float2 cf = __half22float2(sC[srow][wg]);
            fx2 vc = {cf.x, cf.y};
#pragma unroll
            for (int k = 0; k < RPT; ++k) {
                const int t = jr - k;
                if (t >= 0 && t < KS) {               // compile-time resolved
                    p[k]  += tp.g[t] * va;
                    q[k]  += tp.h[t] * va + tp.g[t] * vb;
                    rb[k] += vc;
                }
            }
        }
#pragma unroll
        for (int k = 0; k < RPT; ++k) {
            const int h = h0 + RPT * ty + k;
            const size_t o = nbase + ((size_t)h * L + d) * L + wb + 2*wg;
            __half2 pq[2];
            pq[0] = __floats2half2_rn(p[k].x, q[k].x);
            pq[1] = __floats2half2_rn(p[k].y, q[k].y);
            *reinterpret_cast<int2*>(&PQ[o]) = *reinterpret_cast<int2*>(pq);
            __half2 rr = __floats2half2_rn(rb[k].x, rb[k].y);
            *reinterpret_cast<__half2*>(&Rb[o]) = rr;
        }
    }
}

// ============ Kernel 2: D-conv streaming + |.| + block reduce ================
__global__ __launch_bounds__(512) void k_d(const __half2* __restrict__ PQ,
                                           const __half* __restrict__ R,
                                           float* __restrict__ partial,
                                           Taps tp) {
    const int tx = threadIdx.x;          // 0..31 (w)
    const int ty = threadIdx.y;          // 0..15 (h)
    const int w  = blockIdx.x * 32 + tx;
    const int h  = blockIdx.y * 16 + ty;
    const int gz = blockIdx.z;
    const int n  = gz >> 2;
    const int dc = gz & 3;
    const int d0 = dc * DT;

    const size_t base = (size_t)n * VOL + ((size_t)h * L) * L + w;
    const __half2* PQp = PQ + base;
    const __half*  Rp  = R  + base;

    float rp[KS], rq[KS], rc[KS];
    float box = 0.f;

#pragma unroll
    for (int i = 0; i < KS - 1; ++i) {
        int s = d0 - RAD + i;
        bool ok = (s >= 0);
        int off = s * L;
        float2 pq = make_float2(0.f, 0.f);
        float vc = 0.f;
        if (ok) {
            pq = __half22float2(PQp[off]);
            vc = __half2float(Rp[off]);
        }
        rp[i] = pq.x; rq[i] = pq.y; rc[i] = vc;
        box += vc;
    }

    float acc = 0.f;
#pragma unroll
    for (int k = 0; k < DT; ++k) {
        int s = d0 + RAD + k;
        bool ok = (s < L);
        int off = s * L;
        float2 pq = make_float2(0.f, 0.f);
        float vc = 0.f;
        if (ok) {
            pq = __half22float2(PQp[off]);
            vc = __half2float(Rp[off]);
        }
        const int ri = (KS - 1 + k) % KS;
        rp[ri] = pq.x; rq[ri] = pq.y; rc[ri] = vc;
        box += vc;

        float f = 0.f;
#pragma unroll
        for (int t = 0; t < KS; ++t) {
            const int ii = (k + t) % KS;
            f += tp.h[t] * rp[ii] + tp.g[t] * rq[ii];
        }
        f -= tp.m * box;
        acc += fabsf(f);

        box -= rc[k % KS];
    }
    acc *= tp.scale;

#pragma unroll
    for (int off = 32; off > 0; off >>= 1) acc += __shfl_down(acc, off);

    __shared__ float wsum[8];
    const int tid  = ty * 32 + tx;
    const int lane = tid & 63;
    const int wid  = tid >> 6;
    if (lane == 0) wsum[wid] = acc;
    __syncthreads();
    if (wid == 0) {
        float v = (lane < 8) ? wsum[lane] : 0.f;
#pragma unroll
        for (int off = 4; off > 0; off >>= 1) v += __shfl_down(v, off);
        if (lane == 0) {
            const int bid = (gz * gridDim.y + blockIdx.y) * gridDim.x + blockIdx.x;
            partial[bid] = v;
        }
    }
}

// ============ Final: sum 800 partials, single block, plain store ============
__global__ __launch_bounds__(1024) void k_reduce(const float* __restrict__ partial,
                                                 float* __restrict__ out) {
    float v = 0.f;
    for (int i = threadIdx.x; i < NBLK; i += 1024) v += partial[i];
#pragma unroll
    for (int off = 32; off > 0; off >>= 1) v += __shfl_down(v, off);

    __shared__ float wsum[16];
    const int lane = threadIdx.x & 63;
    const int wid  = threadIdx.x >> 6;
    if (lane == 0) wsum[wid] = v;
    __syncthreads();
    if (wid == 0) {
        float s = (lane < 16) ? wsum[lane] : 0.f;
#pragma unroll
        for (int off = 8; off > 0; off >>= 1) s += __shfl_down(s, off);
        if (lane == 0) out[0] = s;
    }
}

extern "C" void kernel_launch(void* const* d_in, const int* in_sizes, int n_in,
                              void* d_out, int out_size, void* d_ws, size_t ws_size,
                              hipStream_t stream) {
    const float* pred = (const float*)d_in[0];
    const float* tgt  = (const float*)d_in[1];
    float* out = (float*)d_out;

    Taps tp;
    const double sigma = 1.5;
    double g1[KS], S = 0.0;
    for (int i = 0; i < KS; ++i) {
        double x = (double)(i - RAD);
        g1[i] = exp(-x * x / (2.0 * sigma * sigma));
        S += g1[i];
    }
    double sumH = 0.0;
    for (int i = 0; i < KS; ++i) {
        double x = (double)(i - RAD);
        double G = g1[i] / S;
        double H = (x * x - sigma * sigma) / (sigma * sigma * sigma * sigma) * G;
        tp.g[i] = (float)G;
        tp.h[i] = (float)H;
        sumH += H;
    }
    tp.m     = (float)(3.0 * sumH / (double)(KS * KS * KS));
    tp.scale = 1.0f / ((float)NB * (float)VOL);

    // ws layout (bytes): PQ half2 [NB*VOL*4] | R half [NB*VOL*2] | partial f32
    char* wsb = (char*)d_ws;
    __half2* PQ      = (__half2*)wsb;
    __half*  Rb      = (__half*)(wsb + (size_t)NB * VOL * 4);
    float*   partial = (float*)(wsb + (size_t)NB * VOL * 6);

    k_wh<<<dim3(10, L, NB), dim3(256), 0, stream>>>(pred, tgt, PQ, Rb, tp);
    k_d<<<dim3(5, 10, NB * 4), dim3(32, 16), 0, stream>>>(PQ, Rb, partial, tp);
    k_reduce<<<1, 1024, 0, stream>>>(partial, out);
}

// Round 11
// 112.485 us; speedup vs baseline: 1.5553x; 1.1392x over previous
//
#include <hip/hip_runtime.h>
#include <hip/hip_fp16.h>
#include <math.h>

#define KS   15
#define RAD  7
#define L    160
#define VOL  (L*L*L)
#define NB   4
#define WTL  32             // w-cols per k_wh block
#define HTL  80             // output h-rows per k_wh block
#define HALO (HTL + 2*RAD)  // 94
#define LDA  34             // LDS row stride in floats (even, bank-skewed)
#define RPT  5              // h-rows per thread in stage B (16 ty * 5 = 80)
#define DT   40             // k_d d-chunk per thread
#define NBLK (5*10*16)      // k_d grid blocks = 800

typedef float fx2 __attribute__((ext_vector_type(2)));
typedef float fx4 __attribute__((ext_vector_type(4)));

struct Taps {
    float g[KS];   // normalized 1D gaussian (symmetric)
    float h[KS];   // (x^2 - s^2)/s^4 * g (symmetric)
    float m;       // kernel mean (subtracted constant)
    float scale;   // 1 / (N * VOL)
};

// zero-padded fx4 load from a row of length L
__device__ __forceinline__ fx4 ld4z(const float* __restrict__ p, int w) {
    if (w >= 0 && w + 3 < L) return *reinterpret_cast<const fx4*>(p + w);
    fx4 r;
    r.x = (w     >= 0 && w     < L) ? p[w]     : 0.f;
    r.y = (w + 1 >= 0 && w + 1 < L) ? p[w + 1] : 0.f;
    r.z = (w + 2 >= 0 && w + 2 < L) ? p[w + 2] : 0.f;
    r.w = (w + 3 >= 0 && w + 3 < L) ? p[w + 3] : 0.f;
    return r;
}

// ============ Kernel 1: diff + W-conv + H-conv fused ========================
// grid (10 = 5 w-tiles x 2 h-tiles, 160 d, 4 n), block 256.
// XCD swizzle: the 10 blocks of one (d,n) plane-group land on ONE XCD so
// halo re-reads hit that XCD's L2 (plane working set 205 KB << 4 MB).
// Writes PQ (half2) and R (half), TRANSPOSED [n][h][d][w].
__global__ __launch_bounds__(256) void k_wh(const float* __restrict__ pred,
                                            const float* __restrict__ tgt,
                                            __half2* __restrict__ PQ,
                                            __half* __restrict__ Rb,
                                            Taps tp) {
    __shared__ float   sA[HALO][LDA];
    __shared__ float   sB[HALO][LDA];
    __shared__ __half2 sC[HALO][LDA / 2];

    // ---- bijective XCD-chunked remap (nwg=6400, 8 XCDs, chunk=800) ----
    // physical flat id p -> XCD ~ p%8; give XCD x the logical range [x*800,..)
    {
    }
    const int pflat = blockIdx.x + 10 * (blockIdx.y + 160 * blockIdx.z);
    const int wlog  = (pflat & 7) * 800 + (pflat >> 3);
    const int bxs   = wlog % 10;
    const int bys   = (wlog / 10) % 160;
    const int bzs   = wlog / 1600;

    const int tid = threadIdx.x;
    const int wt  = bxs >> 1;                 // 0..4
    const int ht  = bxs & 1;                  // 0..1
    const int wb  = wt * WTL;
    const int h0  = ht * HTL;
    const int d   = bys;
    const int n   = bzs;
    const size_t nbase = (size_t)n * VOL;
    const float* __restrict__ pro = pred + nbase + (size_t)d * L * L;
    const float* __restrict__ tro = tgt  + nbase + (size_t)d * L * L;
    const bool wedge = (wt == 0) || (wt == 4);

    // ---- Stage A: diff + W-conv. 94 rows x 4 groups, 8 outputs/task ----
    for (int task = tid; task < HALO * 4; task += 256) {
        const int r  = task >> 2;             // 0..93
        const int j2 = task & 3;              // 0..3
        const int h  = h0 - RAD + r;
        if (h >= 0 && h < L) {
            const float* pr = pro + h * L;
            const float* tr = tro + h * L;
            const int w0 = wb + 8 * j2 - 8;   // 24-float window base
            float dv[24];
            if (!wedge) {
#pragma unroll
                for (int q = 0; q < 6; ++q) {
                    fx4 pv = *reinterpret_cast<const fx4*>(pr + w0 + 4 * q);
                    fx4 tv = *reinterpret_cast<const fx4*>(tr + w0 + 4 * q);
                    fx4 dd = pv - tv;         // packed f32 sub
                    dv[4*q+0] = dd.x; dv[4*q+1] = dd.y;
                    dv[4*q+2] = dd.z; dv[4*q+3] = dd.w;
                }
            } else {
#pragma unroll
                for (int q = 0; q < 6; ++q) {
                    fx4 pv = ld4z(pr, w0 + 4 * q);
                    fx4 tv = ld4z(tr, w0 + 4 * q);
                    fx4 dd = pv - tv;
                    dv[4*q+0] = dd.x; dv[4*q+1] = dd.y;
                    dv[4*q+2] = dd.z; dv[4*q+3] = dd.w;
                }
            }
            // conv over k-pairs with packed f32 (v_pk_fma_f32)
#pragma unroll
            for (int kp = 0; kp < 8; kp += 2) {
                fx2 mid = {dv[kp + 8], dv[kp + 9]};
                fx2 aa = tp.g[7] * mid;
                fx2 bb = tp.h[7] * mid;
                fx2 cc = mid;
#pragma unroll
                for (int u = 0; u < 7; ++u) {         // symmetric taps
                    fx2 sl = {dv[kp + 1 + u],  dv[kp + 2 + u]};
                    fx2 sr = {dv[kp + 15 - u], dv[kp + 16 - u]};
                    fx2 s  = sl + sr;
                    aa += tp.g[u] * s;
                    bb += tp.h[u] * s;
                    cc += s;
                }
                *reinterpret_cast<fx2*>(&sA[r][8*j2 + kp]) = aa;
                *reinterpret_cast<fx2*>(&sB[r][8*j2 + kp]) = bb;
                sC[r][(8*j2 + kp) >> 1] = __floats2half2_rn(cc.x, cc.y);
            }
        } else {
#pragma unroll
            for (int kp = 0; kp < 8; kp += 2) {
                fx2 z = {0.f, 0.f};
                *reinterpret_cast<fx2*>(&sA[r][8*j2 + kp]) = z;
                *reinterpret_cast<fx2*>(&sB[r][8*j2 + kp]) = z;
                sC[r][(8*j2 + kp) >> 1] = __floats2half2_rn(0.f, 0.f);
            }
        }
    }
    __syncthreads();

    // ---- Stage B: H-conv; thread owns 2 w-cols x RPT h-rows ----
    {
        const int wg = tid & 15;              // 0..15 -> w = wb + 2*wg, +1
        const int ty = tid >> 4;              // 0..15 -> h = h0 + 5*ty .. +4
        fx2 p[RPT], q[RPT], rb[RPT];
#pragma unroll
        for (int k = 0; k < RPT; ++k) { p[k] = 0.f; q[k] = 0.f; rb[k] = 0.f; }
#pragma unroll
        for (int jr = 0; jr < RPT + 2 * RAD; ++jr) {   // 19 rows
            const int srow = RPT * ty + jr;
            fx2 va = *reinterpret_cast<const fx2*>(&sA[srow][2*wg]);
            fx2 vb = *reinterpret_cast<const fx2*>(&sB[srow][2*wg]);
            float2 cf = __half22float2(sC[srow][wg]);
            fx2 vc = {cf.x, cf.y};
#pragma unroll
            for (int k = 0; k < RPT; ++k) {
                const int t = jr - k;
                if (t >= 0 && t < KS) {               // compile-time resolved
                    p[k]  += tp.g[t] * va;
                    q[k]  += tp.h[t] * va + tp.g[t] * vb;
                    rb[k] += vc;
                }
            }
        }
#pragma unroll
        for (int k = 0; k < RPT; ++k) {
            const int h = h0 + RPT * ty + k;
            const size_t o = nbase + ((size_t)h * L + d) * L + wb + 2*wg;
            __half2 pq[2];
            pq[0] = __floats2half2_rn(p[k].x, q[k].x);
            pq[1] = __floats2half2_rn(p[k].y, q[k].y);
            *reinterpret_cast<int2*>(&PQ[o]) = *reinterpret_cast<int2*>(pq);
            __half2 rr = __floats2half2_rn(rb[k].x, rb[k].y);
            *reinterpret_cast<__half2*>(&Rb[o]) = rr;
        }
    }
}

// ============ Kernel 2: D-conv streaming + |.| + block reduce ================
// grid (5,10,16) = 800 blocks. XCD swizzle: the 4 d-chunks of one (bx,by,n)
// group (which share +-7 halo planes) land on one XCD.
__global__ __launch_bounds__(512) void k_d(const __half2* __restrict__ PQ,
                                           const __half* __restrict__ R,
                                           float* __restrict__ partial,
                                           Taps tp) {
    // bijective remap: nwg=800, chunk=100; logical order has dc fastest.
    const int pflat = blockIdx.x + 5 * (blockIdx.y + 10 * blockIdx.z);
    const int wlog  = (pflat & 7) * 100 + (pflat >> 3);
    const int dc    = wlog & 3;
    const int rest  = wlog >> 2;
    const int bx    = rest % 5;
    const int by    = (rest / 5) % 10;
    const int n     = rest / 50;

    const int tx = threadIdx.x;          // 0..31 (w)
    const int ty = threadIdx.y;          // 0..15 (h)
    const int w  = bx * 32 + tx;
    const int h  = by * 16 + ty;
    const int d0 = dc * DT;

    const size_t base = (size_t)n * VOL + ((size_t)h * L) * L + w;
    const __half2* PQp = PQ + base;
    const __half*  Rp  = R  + base;

    float rp[KS], rq[KS], rc[KS];
    float box = 0.f;

#pragma unroll
    for (int i = 0; i < KS - 1; ++i) {
        int s = d0 - RAD + i;
        bool ok = (s >= 0);
        int off = s * L;
        float2 pq = make_float2(0.f, 0.f);
        float vc = 0.f;
        if (ok) {
            pq = __half22float2(PQp[off]);
            vc = __half2float(Rp[off]);
        }
        rp[i] = pq.x; rq[i] = pq.y; rc[i] = vc;
        box += vc;
    }

    float acc = 0.f;
#pragma unroll
    for (int k = 0; k < DT; ++k) {
        int s = d0 + RAD + k;
        bool ok = (s < L);
        int off = s * L;
        float2 pq = make_float2(0.f, 0.f);
        float vc = 0.f;
        if (ok) {
            pq = __half22float2(PQp[off]);
            vc = __half2float(Rp[off]);
        }
        const int ri = (KS - 1 + k) % KS;
        rp[ri] = pq.x; rq[ri] = pq.y; rc[ri] = vc;
        box += vc;

        float f = 0.f;
#pragma unroll
        for (int t = 0; t < KS; ++t) {
            const int ii = (k + t) % KS;
            f += tp.h[t] * rp[ii] + tp.g[t] * rq[ii];
        }
        f -= tp.m * box;
        acc += fabsf(f);

        box -= rc[k % KS];
    }
    acc *= tp.scale;

#pragma unroll
    for (int off = 32; off > 0; off >>= 1) acc += __shfl_down(acc, off);

    __shared__ float wsum[8];
    const int tid  = ty * 32 + tx;
    const int lane = tid & 63;
    const int wid  = tid >> 6;
    if (lane == 0) wsum[wid] = acc;
    __syncthreads();
    if (wid == 0) {
        float v = (lane < 8) ? wsum[lane] : 0.f;
#pragma unroll
        for (int off = 4; off > 0; off >>= 1) v += __shfl_down(v, off);
        if (lane == 0) {
            partial[wlog] = v;   // wlog is a bijection of flat id -> unique slot
        }
    }
}

// ============ Final: sum 800 partials, single block, plain store ============
__global__ __launch_bounds__(1024) void k_reduce(const float* __restrict__ partial,
                                                 float* __restrict__ out) {
    float v = 0.f;
    for (int i = threadIdx.x; i < NBLK; i += 1024) v += partial[i];
#pragma unroll
    for (int off = 32; off > 0; off >>= 1) v += __shfl_down(v, off);

    __shared__ float wsum[16];
    const int lane = threadIdx.x & 63;
    const int wid  = threadIdx.x >> 6;
    if (lane == 0) wsum[wid] = v;
    __syncthreads();
    if (wid == 0) {
        float s = (lane < 16) ? wsum[lane] : 0.f;
#pragma unroll
        for (int off = 8; off > 0; off >>= 1) s += __shfl_down(s, off);
        if (lane == 0) out[0] = s;
    }
}

extern "C" void kernel_launch(void* const* d_in, const int* in_sizes, int n_in,
                              void* d_out, int out_size, void* d_ws, size_t ws_size,
                              hipStream_t stream) {
    const float* pred = (const float*)d_in[0];
    const float* tgt  = (const float*)d_in[1];
    float* out = (float*)d_out;

    Taps tp;
    const double sigma = 1.5;
    double g1[KS], S = 0.0;
    for (int i = 0; i < KS; ++i) {
        double x = (double)(i - RAD);
        g1[i] = exp(-x * x / (2.0 * sigma * sigma));
        S += g1[i];
    }
    double sumH = 0.0;
    for (int i = 0; i < KS; ++i) {
        double x = (double)(i - RAD);
        double G = g1[i] / S;
        double H = (x * x - sigma * sigma) / (sigma * sigma * sigma * sigma) * G;
        tp.g[i] = (float)G;
        tp.h[i] = (float)H;
        sumH += H;
    }
    tp.m     = (float)(3.0 * sumH / (double)(KS * KS * KS));
    tp.scale = 1.0f / ((float)NB * (float)VOL);

    // ws layout (bytes): PQ half2 [NB*VOL*4] | R half [NB*VOL*2] | partial f32
    char* wsb = (char*)d_ws;
    __half2* PQ      = (__half2*)wsb;
    __half*  Rb      = (__half*)(wsb + (size_t)NB * VOL * 4);
    float*   partial = (float*)(wsb + (size_t)NB * VOL * 6);

    k_wh<<<dim3(10, L, NB), dim3(256), 0, stream>>>(pred, tgt, PQ, Rb, tp);
    k_d<<<dim3(5, 10, NB * 4), dim3(32, 16), 0, stream>>>(PQ, Rb, partial, tp);
    k_reduce<<<1, 1024, 0, stream>>>(partial, out);
}